// Round 1
// baseline (1169.009 us; speedup 1.0000x reference)
//
#include <hip/hip_runtime.h>

// QuantizedBottleneck: 1x1 conv(256->64)+BN, 3x3 conv(64->64,pad1)+BN,
// 1x1 conv(64->256)+BN, requantized residual add. All exact integer math.
//
// Shapes: B=32, Cin=Cout=256, width=64, H=W=56. NCHW layout throughout.
// Intermediates t1m/t2m stored as int8 (value - next conv's z_in) in d_ws.

#define B 32
#define CIN 256
#define CMID 64
#define HW 3136      // 56*56
#define WIDTH 56

__device__ __forceinline__ int requant_q(int acc, int M0, int shift, int zout) {
    long long prod = (long long)acc * (long long)M0;
    long long nudge = (prod >= 0) ? (1LL << 30) : (1LL - (1LL << 30));
    long long hi = (prod + nudge) >> 31;            // rounding-doubling high mul
    long long r = (hi + (1LL << (shift - 1))) >> shift;  // rounding right shift
    int v = (int)r + zout;
    return v < 0 ? 0 : (v > 255 ? 255 : v);
}

__device__ __forceinline__ long long mulshift_ll(long long v, int M0, int shift) {
    long long prod = v * (long long)M0;
    long long nudge = (prod >= 0) ? (1LL << 30) : (1LL - (1LL << 30));
    long long hi = (prod + nudge) >> 31;
    return (hi + (1LL << (shift - 1))) >> shift;
}

// ---------------- Kernel 1: conv1 (1x1, 256->64) + bn1 -> t1m int8 ----------
// grid: (49, 4, 32), block 256. lane = hw within 64-chunk, cq picks co group.
__global__ __launch_bounds__(256) void k_conv1(
    const int* __restrict__ x, const float* __restrict__ w1,
    const float* __restrict__ bn_w, const float* __restrict__ bn_b,
    const int* __restrict__ conv_zin, const int* __restrict__ conv_m0,
    const int* __restrict__ conv_shift, const int* __restrict__ conv_zout,
    const int* __restrict__ bn_m0, const int* __restrict__ bn_shift,
    const int* __restrict__ bn_zout,
    signed char* __restrict__ t1m)
{
    const int lane = threadIdx.x & 63;
    const int cq = threadIdx.x >> 6;                 // 0..3
    const int hw = blockIdx.x * 64 + lane;           // 0..3135
    const int co0 = blockIdx.y * 16 + cq * 4;        // 4 channels per thread
    const int b = blockIdx.z;

    const int zin = conv_zin[0];
    const int* xp = x + (size_t)b * CIN * HW + hw;

    float acc[4] = {0.f, 0.f, 0.f, 0.f};
    for (int ci = 0; ci < CIN; ++ci) {
        float xv = (float)(xp[(size_t)ci * HW] - zin);
        const float* wp = w1 + (size_t)co0 * CIN + ci;
#pragma unroll
        for (int j = 0; j < 4; ++j)
            acc[j] = fmaf(xv, wp[(size_t)j * CIN], acc[j]);
    }

    const int cm0 = conv_m0[0], csh = conv_shift[0], czo = conv_zout[0];
    const int bm0 = bn_m0[0], bsh = bn_shift[0], bzo = bn_zout[0];
    const int zin2 = conv_zin[1];
#pragma unroll
    for (int j = 0; j < 4; ++j) {
        int co = co0 + j;
        int q = requant_q((int)acc[j], cm0, csh, czo);
        int a2 = (q - czo) * (int)bn_w[co] + (int)bn_b[co];
        int q2 = requant_q(a2, bm0, bsh, bzo);
        t1m[(size_t)(b * CMID + co) * HW + hw] = (signed char)(q2 - zin2);
    }
}

// ---------------- Kernel 2: conv2 (3x3, 64->64, pad1) + bn2 -> t2m int8 -----
// grid: (49, 4, 32), block 256.
__global__ __launch_bounds__(256) void k_conv2(
    const signed char* __restrict__ t1m, const float* __restrict__ w2,
    const float* __restrict__ bn_w, const float* __restrict__ bn_b,
    const int* __restrict__ conv_zin, const int* __restrict__ conv_m0,
    const int* __restrict__ conv_shift, const int* __restrict__ conv_zout,
    const int* __restrict__ bn_m0, const int* __restrict__ bn_shift,
    const int* __restrict__ bn_zout,
    signed char* __restrict__ t2m)
{
    const int lane = threadIdx.x & 63;
    const int cq = threadIdx.x >> 6;
    const int hw = blockIdx.x * 64 + lane;
    const int co0 = blockIdx.y * 16 + cq * 4;
    const int b = blockIdx.z;
    const int h = hw / WIDTH, w = hw - h * WIDTH;

    float acc[4] = {0.f, 0.f, 0.f, 0.f};
    const signed char* tb = t1m + (size_t)b * CMID * HW;

    for (int kh = 0; kh < 3; ++kh) {
        int y = h + kh - 1;
        if ((unsigned)y >= (unsigned)WIDTH) continue;
        for (int kw = 0; kw < 3; ++kw) {
            int xw = w + kw - 1;
            if ((unsigned)xw >= (unsigned)WIDTH) continue;
            const signed char* tp = tb + y * WIDTH + xw;
            const float* wp = w2 + kh * 3 + kw;
            for (int ci = 0; ci < CMID; ++ci) {
                float xv = (float)tp[(size_t)ci * HW];
                const float* wq = wp + (size_t)ci * 9;
#pragma unroll
                for (int j = 0; j < 4; ++j)
                    acc[j] = fmaf(xv, wq[(size_t)(co0 + j) * CMID * 9], acc[j]);
            }
        }
    }

    const int cm0 = conv_m0[1], csh = conv_shift[1], czo = conv_zout[1];
    const int bm0 = bn_m0[1], bsh = bn_shift[1], bzo = bn_zout[1];
    const int zin3 = conv_zin[2];
#pragma unroll
    for (int j = 0; j < 4; ++j) {
        int co = co0 + j;
        int q = requant_q((int)acc[j], cm0, csh, czo);
        int a2 = (q - czo) * (int)bn_w[co] + (int)bn_b[co];
        int q2 = requant_q(a2, bm0, bsh, bzo);
        t2m[(size_t)(b * CMID + co) * HW + hw] = (signed char)(q2 - zin3);
    }
}

// ------------- Kernel 3: conv3 (1x1, 64->256) + bn3 + residual add ----------
// grid: (49, 16, 32), block 256.
__global__ __launch_bounds__(256) void k_conv3(
    const signed char* __restrict__ t2m, const float* __restrict__ w3,
    const float* __restrict__ bn_w, const float* __restrict__ bn_b,
    const int* __restrict__ x,
    const int* __restrict__ conv_m0, const int* __restrict__ conv_shift,
    const int* __restrict__ conv_zout,
    const int* __restrict__ bn_m0, const int* __restrict__ bn_shift,
    const int* __restrict__ bn_zout,
    const int* __restrict__ add_z, const int* __restrict__ add_m0,
    const int* __restrict__ add_shift, const int* __restrict__ add_zout,
    int* __restrict__ out)
{
    const int lane = threadIdx.x & 63;
    const int cq = threadIdx.x >> 6;
    const int hw = blockIdx.x * 64 + lane;
    const int co0 = blockIdx.y * 16 + cq * 4;        // of 256
    const int b = blockIdx.z;

    const signed char* tp = t2m + (size_t)b * CMID * HW + hw;

    float acc[4] = {0.f, 0.f, 0.f, 0.f};
    for (int ci = 0; ci < CMID; ++ci) {
        float xv = (float)tp[(size_t)ci * HW];
        const float* wp = w3 + (size_t)co0 * CMID + ci;
#pragma unroll
        for (int j = 0; j < 4; ++j)
            acc[j] = fmaf(xv, wp[(size_t)j * CMID], acc[j]);
    }

    const int cm0 = conv_m0[2], csh = conv_shift[2], czo = conv_zout[2];
    const int bm0 = bn_m0[2], bsh = bn_shift[2], bzo = bn_zout[2];
    const int az0 = add_z[0], az1 = add_z[1];
    const int am0 = add_m0[0], am1 = add_m0[1];
    const int ash0 = add_shift[0], ash1 = add_shift[1];
    const int azout = add_zout[0];

#pragma unroll
    for (int j = 0; j < 4; ++j) {
        int co = co0 + j;
        int q = requant_q((int)acc[j], cm0, csh, czo);
        int a2 = (q - czo) * (int)bn_w[co] + (int)bn_b[co];
        int q2 = requant_q(a2, bm0, bsh, bzo);
        size_t idx = (size_t)(b * CIN + co) * HW + hw;
        int idv = x[idx];
        long long ra = mulshift_ll((long long)(idv - az0), am0, ash0);
        long long rb = mulshift_ll((long long)(q2 - az1), am1, ash1);
        int res = (int)(ra + rb) + azout;
        res = res < 0 ? 0 : (res > 255 ? 255 : res);
        out[idx] = res;
    }
}

extern "C" void kernel_launch(void* const* d_in, const int* in_sizes, int n_in,
                              void* d_out, int out_size, void* d_ws, size_t ws_size,
                              hipStream_t stream) {
    const int* x = (const int*)d_in[0];
    const float* w1 = (const float*)d_in[1];
    const float* w2 = (const float*)d_in[2];
    const float* w3 = (const float*)d_in[3];
    const float* bn1_w = (const float*)d_in[4];
    const float* bn1_b = (const float*)d_in[5];
    const float* bn2_w = (const float*)d_in[6];
    const float* bn2_b = (const float*)d_in[7];
    const float* bn3_w = (const float*)d_in[8];
    const float* bn3_b = (const float*)d_in[9];
    const int* conv_zin = (const int*)d_in[10];
    const int* conv_m0 = (const int*)d_in[11];
    const int* conv_shift = (const int*)d_in[12];
    const int* conv_zout = (const int*)d_in[13];
    const int* bn_m0 = (const int*)d_in[14];
    const int* bn_shift = (const int*)d_in[15];
    const int* bn_zout = (const int*)d_in[16];
    const int* add_z = (const int*)d_in[17];
    const int* add_m0 = (const int*)d_in[18];
    const int* add_shift = (const int*)d_in[19];
    const int* add_zout = (const int*)d_in[20];

    signed char* t1m = (signed char*)d_ws;
    signed char* t2m = t1m + (size_t)B * CMID * HW;   // +6,422,528 B

    dim3 blk(256);
    dim3 g1(49, 4, 32);    // 64 hw-lanes x (4 cq * 4 co/thread * 4 by) = 64 co
    dim3 g3(49, 16, 32);   // 256 co

    k_conv1<<<g1, blk, 0, stream>>>(x, w1, bn1_w, bn1_b,
        conv_zin, conv_m0, conv_shift, conv_zout, bn_m0, bn_shift, bn_zout, t1m);
    k_conv2<<<g1, blk, 0, stream>>>(t1m, w2, bn2_w, bn2_b,
        conv_zin, conv_m0, conv_shift, conv_zout, bn_m0, bn_shift, bn_zout, t2m);
    k_conv3<<<g3, blk, 0, stream>>>(t2m, w3, bn3_w, bn3_b, x,
        conv_m0, conv_shift, conv_zout, bn_m0, bn_shift, bn_zout,
        add_z, add_m0, add_shift, add_zout, (int*)d_out);
}

// Round 2
// 286.938 us; speedup vs baseline: 4.0741x; 4.0741x over previous
//
#include <hip/hip_runtime.h>

// QuantizedBottleneck via i8 MFMA implicit GEMM. All exact integer math:
//   conv1: M=64  K=256 (x int32 -> i8 inline)          -> t1 [n][64] i8
//   conv2: M=64  K=9*64 (3x3, halo LDS slab per 2 rows) -> t2 [n][64] i8
//   conv3: M=256 K=64  + BN + requantized residual add  -> out int32
// t1/t2 hold (q - next_zin) so zero-padding == zero bytes.
// MFMA 16x16x64_i8 layouts (m89-family): A[m=lane&15][k=(lane>>4)*16+j],
// B[k=(lane>>4)*16+j][n=lane&15], C/D: col=lane&15, row=(lane>>4)*4+reg.

typedef int v4i __attribute__((ext_vector_type(4)));

#define BATCH 32
#define CIN 256
#define CMID 64
#define HW 3136
#define W56 56

__device__ __forceinline__ int requant_q(int acc, int M0, int shift, int zout) {
    long long prod = (long long)acc * (long long)M0;
    long long nudge = (prod >= 0) ? (1LL << 30) : (1LL - (1LL << 30));
    long long hi = (prod + nudge) >> 31;
    long long r = (hi + (1LL << (shift - 1))) >> shift;
    int v = (int)r + zout;
    return v < 0 ? 0 : (v > 255 ? 255 : v);
}

__device__ __forceinline__ long long mulshift_ll(long long v, int M0, int shift) {
    long long prod = v * (long long)M0;
    long long nudge = (prod >= 0) ? (1LL << 30) : (1LL - (1LL << 30));
    long long hi = (prod + nudge) >> 31;
    return (hi + (1LL << (shift - 1))) >> shift;
}

// pack 16 small ints (from float weights) into a v4i i8 fragment
__device__ __forceinline__ v4i pack16f(const float* src, int stride) {
    v4i r;
#pragma unroll
    for (int d = 0; d < 4; ++d) {
        unsigned int u = 0;
#pragma unroll
        for (int by = 0; by < 4; ++by) {
            int v = (int)src[(d * 4 + by) * stride];
            u |= ((unsigned int)(v & 255)) << (8 * by);
        }
        r[d] = (int)u;
    }
    return r;
}

// ---------------- conv1: 1x1 256->64 + bn1 -> t1 [n][64] i8 -----------------
// grid (784), block 256. n-tile = 128 flat pixels. 4 waves = 4 co-strips of 16.
__global__ __launch_bounds__(256) void k_conv1(
    const int* __restrict__ x, const float* __restrict__ w1,
    const float* __restrict__ bn_w, const float* __restrict__ bn_b,
    const int* __restrict__ conv_zin, const int* __restrict__ conv_m0,
    const int* __restrict__ conv_shift, const int* __restrict__ conv_zout,
    const int* __restrict__ bn_m0, const int* __restrict__ bn_shift,
    const int* __restrict__ bn_zout, signed char* __restrict__ t1)
{
    __shared__ v4i sm[640];                     // 128 pixels x 80B (64 ci + pad)
    const int tid = threadIdx.x, lane = tid & 63, wv = tid >> 6;
    const int col = lane & 15, koff = lane >> 4;
    const int nbase = blockIdx.x * 128;
    const int co0 = wv * 16;

    // A fragments: w1[co][ci], 4 K-steps of 64
    v4i a[4];
#pragma unroll
    for (int ks = 0; ks < 4; ++ks)
        a[ks] = pack16f(w1 + (size_t)(co0 + col) * 256 + ks * 64 + koff * 16, 1);

    // staging coords: 128 pixels x 2 ci-halves
    const int p = tid & 127, ch = tid >> 7;
    const int np = nbase + p;
    const int pb = np / HW, phw = np - pb * HW;
    const int zin = conv_zin[0];

    v4i acc[8];
#pragma unroll
    for (int i = 0; i < 8; ++i) acc[i] = (v4i){0, 0, 0, 0};

    for (int ks = 0; ks < 4; ++ks) {
        // pack 32 ci for my pixel into 8 dwords (coalesced along pixels)
        unsigned int pk[8];
        const size_t xb = ((size_t)pb * CIN + ks * 64 + ch * 32) * HW + phw;
#pragma unroll
        for (int d = 0; d < 8; ++d) {
            unsigned int u = 0;
#pragma unroll
            for (int by = 0; by < 4; ++by) {
                int v = x[xb + (size_t)(d * 4 + by) * HW] - zin;
                u |= ((unsigned int)(v & 255)) << (8 * by);
            }
            pk[d] = u;
        }
        __syncthreads();                       // prior reads of sm complete
        v4i* dst = &sm[p * 5 + ch * 2];
        v4i w0, w1v;
        w0[0] = (int)pk[0]; w0[1] = (int)pk[1]; w0[2] = (int)pk[2]; w0[3] = (int)pk[3];
        w1v[0] = (int)pk[4]; w1v[1] = (int)pk[5]; w1v[2] = (int)pk[6]; w1v[3] = (int)pk[7];
        dst[0] = w0; dst[1] = w1v;
        __syncthreads();
#pragma unroll
        for (int nt = 0; nt < 8; ++nt) {
            v4i bf = sm[(nt * 16 + col) * 5 + koff];
            acc[nt] = __builtin_amdgcn_mfma_i32_16x16x64_i8(a[ks], bf, acc[nt], 0, 0, 0);
        }
    }

    const int cm0 = conv_m0[0], csh = conv_shift[0], czo = conv_zout[0];
    const int bm0 = bn_m0[0], bsh = bn_shift[0], bzo = bn_zout[0];
    const int zin2 = conv_zin[1];
    const int rowb = koff * 4;
    int bw[4], bb[4];
#pragma unroll
    for (int r = 0; r < 4; ++r) {
        bw[r] = (int)bn_w[co0 + rowb + r];
        bb[r] = (int)bn_b[co0 + rowb + r];
    }
#pragma unroll
    for (int nt = 0; nt < 8; ++nt) {
        int n = nbase + nt * 16 + col;
        unsigned int pkd = 0;
#pragma unroll
        for (int r = 0; r < 4; ++r) {
            int q = requant_q(acc[nt][r], cm0, csh, czo);
            int a2 = (q - czo) * bw[r] + bb[r];
            int q2 = requant_q(a2, bm0, bsh, bzo);
            pkd |= ((unsigned int)((q2 - zin2) & 255)) << (8 * r);
        }
        *(unsigned int*)(t1 + (size_t)n * 64 + co0 + rowb) = pkd;
    }
}

// ---------------- conv2: 3x3 64->64 pad1 + bn2 -> t2 [n][64] i8 -------------
// grid (28, 32): row-pair x batch. n-tile = 112 (2 rows). halo = 4 rows in LDS.
__global__ __launch_bounds__(256) void k_conv2(
    const signed char* __restrict__ t1, const float* __restrict__ w2,
    const float* __restrict__ bn_w, const float* __restrict__ bn_b,
    const int* __restrict__ conv_zin, const int* __restrict__ conv_m0,
    const int* __restrict__ conv_shift, const int* __restrict__ conv_zout,
    const int* __restrict__ bn_m0, const int* __restrict__ bn_shift,
    const int* __restrict__ bn_zout, signed char* __restrict__ t2)
{
    __shared__ v4i sm[1120];                    // 224 pixels x 80B
    const int tid = threadIdx.x, lane = tid & 63, wv = tid >> 6;
    const int col = lane & 15, koff = lane >> 4;
    const int b = blockIdx.y;
    const int r0 = blockIdx.x * 2;
    const int co0 = wv * 16;

    // A fragments: w2 OIHW [co][ci][kh][kw]; frag tap t, k=ci: stride 9 floats
    v4i a[9];
#pragma unroll
    for (int t = 0; t < 9; ++t)
        a[t] = pack16f(w2 + ((size_t)(co0 + col) * 64 + koff * 16) * 9 + t, 9);

    // stage halo rows r0-1 .. r0+2 (zeros outside image)
    const v4i* t1v = (const v4i*)t1;
#pragma unroll
    for (int k = 0; k < 4; ++k) {
        int idx = tid + k * 256;
        if (idx < 896) {
            int pixl = idx >> 2, part = idx & 3;
            int lrow = pixl / W56, gw = pixl - lrow * W56;
            int grow = r0 - 1 + lrow;
            v4i v = (v4i){0, 0, 0, 0};
            if ((unsigned)grow < 56u)
                v = t1v[(size_t)(b * HW + grow * W56 + gw) * 4 + part];
            sm[pixl * 5 + part] = v;
        }
    }
    __syncthreads();

    v4i acc[7];
#pragma unroll
    for (int i = 0; i < 7; ++i) acc[i] = (v4i){0, 0, 0, 0};

#pragma unroll
    for (int kh = 0; kh < 3; ++kh) {
#pragma unroll
        for (int kw = 0; kw < 3; ++kw) {
            v4i af = a[kh * 3 + kw];
#pragma unroll
            for (int nt = 0; nt < 7; ++nt) {
                int pix = nt * 16 + col;
                int orow = pix >= W56 ? 1 : 0;
                int wc = pix - orow * W56;
                int sr = orow + kh;                 // halo row 0..3
                int sw = wc + kw - 1;
                bool valid = (unsigned)sw < 56u;
                v4i bf = sm[(sr * W56 + (valid ? sw : 0)) * 5 + koff];
                if (!valid) { bf[0] = 0; bf[1] = 0; bf[2] = 0; bf[3] = 0; }
                acc[nt] = __builtin_amdgcn_mfma_i32_16x16x64_i8(af, bf, acc[nt], 0, 0, 0);
            }
        }
    }

    const int cm0 = conv_m0[1], csh = conv_shift[1], czo = conv_zout[1];
    const int bm0 = bn_m0[1], bsh = bn_shift[1], bzo = bn_zout[1];
    const int zin3 = conv_zin[2];
    const int rowb = koff * 4;
    int bw[4], bb[4];
#pragma unroll
    for (int r = 0; r < 4; ++r) {
        bw[r] = (int)bn_w[co0 + rowb + r];
        bb[r] = (int)bn_b[co0 + rowb + r];
    }
#pragma unroll
    for (int nt = 0; nt < 7; ++nt) {
        int pix = nt * 16 + col;
        int n = b * HW + r0 * W56 + pix;
        unsigned int pkd = 0;
#pragma unroll
        for (int r = 0; r < 4; ++r) {
            int q = requant_q(acc[nt][r], cm0, csh, czo);
            int a2 = (q - czo) * bw[r] + bb[r];
            int q2 = requant_q(a2, bm0, bsh, bzo);
            pkd |= ((unsigned int)((q2 - zin3) & 255)) << (8 * r);
        }
        *(unsigned int*)(t2 + (size_t)n * 64 + co0 + rowb) = pkd;
    }
}

// ------------- conv3: 1x1 64->256 + bn3 + requantized residual --------------
// grid (784, 4): n-tile 128 x co-group of 64. 4 waves = 4 co-strips of 16.
__global__ __launch_bounds__(256) void k_conv3(
    const signed char* __restrict__ t2, const float* __restrict__ w3,
    const float* __restrict__ bn_w, const float* __restrict__ bn_b,
    const int* __restrict__ x,
    const int* __restrict__ conv_m0, const int* __restrict__ conv_shift,
    const int* __restrict__ conv_zout,
    const int* __restrict__ bn_m0, const int* __restrict__ bn_shift,
    const int* __restrict__ bn_zout,
    const int* __restrict__ add_z, const int* __restrict__ add_m0,
    const int* __restrict__ add_shift, const int* __restrict__ add_zout,
    int* __restrict__ out)
{
    __shared__ v4i sm[640];
    const int tid = threadIdx.x, lane = tid & 63, wv = tid >> 6;
    const int col = lane & 15, koff = lane >> 4;
    const int nbase = blockIdx.x * 128;
    const int co0 = blockIdx.y * 64 + wv * 16;

    v4i a = pack16f(w3 + (size_t)(co0 + col) * 64 + koff * 16, 1);

    const v4i* t2v = (const v4i*)t2;
#pragma unroll
    for (int k = 0; k < 2; ++k) {
        int idx = tid + k * 256;                // 512 chunks
        int pixl = idx >> 2, part = idx & 3;
        sm[pixl * 5 + part] = t2v[(size_t)(nbase + pixl) * 4 + part];
    }
    __syncthreads();

    v4i acc[8];
#pragma unroll
    for (int i = 0; i < 8; ++i) acc[i] = (v4i){0, 0, 0, 0};
#pragma unroll
    for (int nt = 0; nt < 8; ++nt) {
        v4i bf = sm[(nt * 16 + col) * 5 + koff];
        acc[nt] = __builtin_amdgcn_mfma_i32_16x16x64_i8(a, bf, acc[nt], 0, 0, 0);
    }

    const int cm0 = conv_m0[2], csh = conv_shift[2], czo = conv_zout[2];
    const int bm0 = bn_m0[2], bsh = bn_shift[2], bzo = bn_zout[2];
    const int az0 = add_z[0], az1 = add_z[1];
    const int am0 = add_m0[0], am1 = add_m0[1];
    const int ash0 = add_shift[0], ash1 = add_shift[1];
    const int azout = add_zout[0];
    const int rowb = koff * 4;
    int bw[4], bb[4];
#pragma unroll
    for (int r = 0; r < 4; ++r) {
        bw[r] = (int)bn_w[co0 + rowb + r];
        bb[r] = (int)bn_b[co0 + rowb + r];
    }
#pragma unroll
    for (int nt = 0; nt < 8; ++nt) {
        int n = nbase + nt * 16 + col;
        int pb = n / HW, phw = n - pb * HW;
#pragma unroll
        for (int r = 0; r < 4; ++r) {
            int co = co0 + rowb + r;
            int q = requant_q(acc[nt][r], cm0, csh, czo);
            int a2 = (q - czo) * bw[r] + bb[r];
            int q2 = requant_q(a2, bm0, bsh, bzo);
            size_t ix = ((size_t)pb * CIN + co) * HW + phw;
            int idv = x[ix];
            long long ra = mulshift_ll((long long)(idv - az0), am0, ash0);
            long long rb = mulshift_ll((long long)(q2 - az1), am1, ash1);
            int res = (int)(ra + rb) + azout;
            res = res < 0 ? 0 : (res > 255 ? 255 : res);
            out[ix] = res;
        }
    }
}

extern "C" void kernel_launch(void* const* d_in, const int* in_sizes, int n_in,
                              void* d_out, int out_size, void* d_ws, size_t ws_size,
                              hipStream_t stream) {
    const int* x = (const int*)d_in[0];
    const float* w1 = (const float*)d_in[1];
    const float* w2 = (const float*)d_in[2];
    const float* w3 = (const float*)d_in[3];
    const float* bn1_w = (const float*)d_in[4];
    const float* bn1_b = (const float*)d_in[5];
    const float* bn2_w = (const float*)d_in[6];
    const float* bn2_b = (const float*)d_in[7];
    const float* bn3_w = (const float*)d_in[8];
    const float* bn3_b = (const float*)d_in[9];
    const int* conv_zin = (const int*)d_in[10];
    const int* conv_m0 = (const int*)d_in[11];
    const int* conv_shift = (const int*)d_in[12];
    const int* conv_zout = (const int*)d_in[13];
    const int* bn_m0 = (const int*)d_in[14];
    const int* bn_shift = (const int*)d_in[15];
    const int* bn_zout = (const int*)d_in[16];
    const int* add_z = (const int*)d_in[17];
    const int* add_m0 = (const int*)d_in[18];
    const int* add_shift = (const int*)d_in[19];
    const int* add_zout = (const int*)d_in[20];

    signed char* t1 = (signed char*)d_ws;                       // [100352][64]
    signed char* t2 = t1 + (size_t)BATCH * HW * CMID;           // [100352][64]

    k_conv1<<<dim3(784), dim3(256), 0, stream>>>(x, w1, bn1_w, bn1_b,
        conv_zin, conv_m0, conv_shift, conv_zout, bn_m0, bn_shift, bn_zout, t1);
    k_conv2<<<dim3(28, 32), dim3(256), 0, stream>>>(t1, w2, bn2_w, bn2_b,
        conv_zin, conv_m0, conv_shift, conv_zout, bn_m0, bn_shift, bn_zout, t2);
    k_conv3<<<dim3(784, 4), dim3(256), 0, stream>>>(t2, w3, bn3_w, bn3_b, x,
        conv_m0, conv_shift, conv_zout, bn_m0, bn_shift, bn_zout,
        add_z, add_m0, add_shift, add_zout, (int*)d_out);
}